// Round 1
// baseline (2825.039 us; speedup 1.0000x reference)
//
#include <hip/hip_runtime.h>

// RWKV-7 WKV recurrence. T=4096, H=32 heads, N=64 head size, f32.
//   sa_i = sum_j S[i][j]*a[j];  S[i][j] = S[i][j]*w[j] + sa_i*b[j] + v_i*k[j];
//   x_i  = sum_j S[i][j]*r[j]
// Rows i are independent -> 2048 rows spread over GPU; cols split 16-way per row.
// Wave = 4 rows x 16 colgroups (4 cols each). 512 blocks x 64 threads.
// Inputs staged through a PF-deep LDS ring via global_load_lds + counted vmcnt.

#define T_LEN 4096
#define NH 32
#define HS 64
#define DIM (NH * HS)          // 2048
#define PF 10                  // prefetch depth (6*PF = 60 loads in flight <= 63)
#define X_SIZE (T_LEN * DIM)   // x output elements; state2 follows

// ---- cross-lane butterfly sum over 16-lane groups (all lanes get the sum) ----
__device__ __forceinline__ float red16(float x) {
  // xor1: quad_perm [1,0,3,2] = 0xB1 ; xor2: quad_perm [2,3,0,1] = 0x4E (DPP, ~fast)
  {
    int v = __builtin_amdgcn_update_dpp(0, __float_as_int(x), 0xB1, 0xF, 0xF, true);
    x += __int_as_float(v);
  }
  {
    int v = __builtin_amdgcn_update_dpp(0, __float_as_int(x), 0x4E, 0xF, 0xF, true);
    x += __int_as_float(v);
  }
  // xor4 / xor8 via ds_swizzle BitMode: offset = (xor<<10) | 0x1F
  {
    int v = __builtin_amdgcn_ds_swizzle(__float_as_int(x), 0x101F);
    x += __int_as_float(v);
  }
  {
    int v = __builtin_amdgcn_ds_swizzle(__float_as_int(x), 0x201F);
    x += __int_as_float(v);
  }
  return x;
}

// async global->LDS, 4B per lane, dest = base + lane*4 (wave-uniform base)
__device__ __forceinline__ void gload_lds(const float* g, float* l) {
  __builtin_amdgcn_global_load_lds(
      (const __attribute__((address_space(1))) void*)g,
      (__attribute__((address_space(3))) void*)l, 4, 0, 0);
}

__global__ void __launch_bounds__(64) wkv7_kernel(
    const float* __restrict__ Rp, const float* __restrict__ Wp,
    const float* __restrict__ Kp, const float* __restrict__ Vp,
    const float* __restrict__ Ap, const float* __restrict__ Bp,
    const float* __restrict__ S0, float* __restrict__ OUT) {
  // arrays staged per step: 0=r 1=w 2=k 3=v 4=a 5=b
  __shared__ float lds[PF][6][HS];

  // XCD-aware mapping: blocks b%8 -> XCD b%8 (round-robin dispatch assumption).
  // Each head's 16 blocks stay on one XCD -> HBM fetched once per element.
  const int bid = blockIdx.x;          // 0..511
  const int xcd = bid & 7;
  const int slot = bid >> 3;           // 0..63
  const int head = xcd * 4 + (slot >> 4);  // 4 heads per XCD
  const int rowblk = slot & 15;        // 16 row-blocks of 4 rows
  const int lane = threadIdx.x;        // 0..63
  const int cg = lane & 15;            // colgroup: cols cg*4 .. cg*4+3
  const int tr = lane >> 4;            // row-within-block 0..3
  const int row = rowblk * 4 + tr;     // 0..63 within head
  const int j0 = cg * 4;
  const int hb = head * HS;

  const float* gp[6] = {Rp, Wp, Kp, Vp, Ap, Bp};

  // state row fragment: S[row][j0..j0+3]
  float4 S = *(const float4*)(S0 + (size_t)head * HS * HS + row * HS + j0);

  // ---- preload steps 0..PF-1 into the LDS ring ----
  for (int p = 0; p < PF; ++p) {
    const long off = (long)p * DIM + hb + lane;
#pragma unroll
    for (int q = 0; q < 6; ++q) gload_lds(gp[q] + off, &lds[p][q][0]);
  }
  asm volatile("s_waitcnt vmcnt(54)" ::: "memory");  // step-0 loads done

  // read step-0 operands into registers
  float4 cr = *(float4*)&lds[0][0][j0];
  float4 cw = *(float4*)&lds[0][1][j0];
  float4 ck = *(float4*)&lds[0][2][j0];
  float cv = lds[0][3][row];
  float4 ca = *(float4*)&lds[0][4][j0];
  float4 cb = *(float4*)&lds[0][5][j0];

  for (int t = 0; t < T_LEN; ++t) {
    const int sl = t % PF;
    const int sln = (t + 1) % PF;

    // slot sl's ds_reads (done last iter / preloop) must land before overwrite
    asm volatile("s_waitcnt lgkmcnt(0)" ::: "memory");
    if (t + PF < T_LEN) {
      const long off = (long)(t + PF) * DIM + hb + lane;
#pragma unroll
      for (int q = 0; q < 6; ++q) gload_lds(gp[q] + off, &lds[sl][q][0]);
    }
    // wait until step t+1's 6 loads are retired (FIFO-oldest). Main loop keeps
    // 54 loads in flight; tail (no more issues) drains fully.
    if (t < T_LEN - PF) {
      asm volatile("s_waitcnt vmcnt(54)" ::: "memory");
    } else {
      asm volatile("s_waitcnt vmcnt(0)" ::: "memory");
    }

    // read-ahead step t+1 operands (off critical path; stale-but-safe at t=T-1)
    float4 nr = *(float4*)&lds[sln][0][j0];
    float4 nw = *(float4*)&lds[sln][1][j0];
    float4 nk = *(float4*)&lds[sln][2][j0];
    float nv = lds[sln][3][row];
    float4 na = *(float4*)&lds[sln][4][j0];
    float4 nb = *(float4*)&lds[sln][5][j0];

    // ---- step t ----
    // sa_i partial over 4 cols, then butterfly over the 16-lane row group
    float pa = S.x * ca.x + S.y * ca.y + S.z * ca.z + S.w * ca.w;
    pa = red16(pa);

    // state update
    S.x = S.x * cw.x + pa * cb.x + cv * ck.x;
    S.y = S.y * cw.y + pa * cb.y + cv * ck.y;
    S.z = S.z * cw.z + pa * cb.z + cv * ck.z;
    S.w = S.w * cw.w + pa * cb.w + cv * ck.w;

    // output x_i = S_new . r
    float qx = S.x * cr.x + S.y * cr.y + S.z * cr.z + S.w * cr.w;
    qx = red16(qx);
    if (cg == 0) OUT[(long)t * DIM + hb + row] = qx;

    cr = nr; cw = nw; ck = nk; cv = nv; ca = na; cb = nb;
  }

  // final state2 out: [H, N, N] after the x block
  *(float4*)(OUT + (size_t)X_SIZE + (size_t)head * HS * HS + row * HS + j0) = S;
}

extern "C" void kernel_launch(void* const* d_in, const int* in_sizes, int n_in,
                              void* d_out, int out_size, void* d_ws, size_t ws_size,
                              hipStream_t stream) {
  // setup_inputs order: 0=seq_length(int) 1=r 2=w 3=k 4=v 5=a 6=b 7=state2
  const float* Rp = (const float*)d_in[1];
  const float* Wp = (const float*)d_in[2];
  const float* Kp = (const float*)d_in[3];
  const float* Vp = (const float*)d_in[4];
  const float* Ap = (const float*)d_in[5];
  const float* Bp = (const float*)d_in[6];
  const float* S0 = (const float*)d_in[7];
  wkv7_kernel<<<dim3(512), dim3(64), 0, stream>>>(Rp, Wp, Kp, Vp, Ap, Bp, S0,
                                                  (float*)d_out);
}

// Round 2
// 2596.232 us; speedup vs baseline: 1.0881x; 1.0881x over previous
//
#include <hip/hip_runtime.h>

// RWKV-7 WKV recurrence. T=4096, H=32 heads, N=64 head size, f32.
// Per head-row i: sa_i = dot(S[i], a); S[i] = S[i]*w + sa_i*b + v_i*k;
//                 x_i = dot(S[i], r)  [factored: dot(S_old,w*r) + sa*(b.r) + v*(k.r)]
// 512 blocks x 64 thr. Wave = 4 rows x 16 colgroups (4 cols each).
// Reductions: pure-DPP 16-lane butterfly (quad_perm xor1/xor2 + row_ror:4/8).
// Inputs staged through PF=8 LDS ring via global_load_lds + counted vmcnt.

#define T_LEN 4096
#define NH 32
#define HS 64
#define DIM (NH * HS)          // 2048
#define PF 8                   // 48 loads + ~8 stores in flight <= 63 vmcnt cap
#define X_SIZE (T_LEN * DIM)

template <int CTRL>
__device__ __forceinline__ float dppadd(float x) {
  int v = __builtin_amdgcn_update_dpp(0, __float_as_int(x), CTRL, 0xF, 0xF, true);
  return x + __int_as_float(v);
}

// Four parallel 16-lane butterfly sums, level-interleaved for ILP. No LDS ops.
__device__ __forceinline__ void red16x4(float& a, float& b, float& c, float& d) {
  a = dppadd<0xB1>(a);  b = dppadd<0xB1>(b);  c = dppadd<0xB1>(c);  d = dppadd<0xB1>(d);   // quad_perm xor1
  a = dppadd<0x4E>(a);  b = dppadd<0x4E>(b);  c = dppadd<0x4E>(c);  d = dppadd<0x4E>(d);   // quad_perm xor2
  a = dppadd<0x124>(a); b = dppadd<0x124>(b); c = dppadd<0x124>(c); d = dppadd<0x124>(d);  // row_ror:4
  a = dppadd<0x128>(a); b = dppadd<0x128>(b); c = dppadd<0x128>(c); d = dppadd<0x128>(d);  // row_ror:8
}

__device__ __forceinline__ float dot4(const float4& x, const float4& y) {
  return x.x * y.x + x.y * y.y + x.z * y.z + x.w * y.w;
}

// async global->LDS, 4B/lane, dest = base + lane*4 (wave-uniform base)
__device__ __forceinline__ void gload_lds(const float* g, float* l) {
  __builtin_amdgcn_global_load_lds(
      (const __attribute__((address_space(1))) void*)g,
      (__attribute__((address_space(3))) void*)l, 4, 0, 0);
}

struct Step {
  float4 r, w, k, a, b;
  float v;
};

__global__ void __launch_bounds__(64) wkv7_kernel(
    const float* __restrict__ Rp, const float* __restrict__ Wp,
    const float* __restrict__ Kp, const float* __restrict__ Vp,
    const float* __restrict__ Ap, const float* __restrict__ Bp,
    const float* __restrict__ S0, float* __restrict__ OUT) {
  __shared__ __align__(16) float lds[PF][6][HS];

  // XCD-aware: each head's 16 blocks stay on one XCD for L2 reuse.
  const int bid = blockIdx.x;              // 0..511
  const int xcd = bid & 7;
  const int slot = bid >> 3;               // 0..63
  const int head = xcd * 4 + (slot >> 4);  // 4 heads per XCD
  const int rowblk = slot & 15;
  const int lane = threadIdx.x;            // 0..63
  const int cg = lane & 15;                // colgroup: cols cg*4..cg*4+3
  const int tr = lane >> 4;
  const int row = rowblk * 4 + tr;         // 0..63 within head
  const int j0 = cg * 4;
  const int hb = head * HS;

  // state row fragment S[row][j0..j0+3]
  float4 S = *(const float4*)(S0 + (size_t)head * HS * HS + row * HS + j0);

  // ---- preload steps 0..PF-1 into LDS ring ----
  for (int p = 0; p < PF; ++p) {
    const int off = p * DIM + hb + lane;
    gload_lds(Rp + off, &lds[p][0][0]);
    gload_lds(Wp + off, &lds[p][1][0]);
    gload_lds(Kp + off, &lds[p][2][0]);
    gload_lds(Vp + off, &lds[p][3][0]);
    gload_lds(Ap + off, &lds[p][4][0]);
    gload_lds(Bp + off, &lds[p][5][0]);
  }
  asm volatile("s_waitcnt vmcnt(42)" ::: "memory");  // slot-0 loads retired

  Step c0, c1;
  c0.r = *(float4*)&lds[0][0][j0];
  c0.w = *(float4*)&lds[0][1][j0];
  c0.k = *(float4*)&lds[0][2][j0];
  c0.v = lds[0][3][row];
  c0.a = *(float4*)&lds[0][4][j0];
  c0.b = *(float4*)&lds[0][5][j0];

  auto body = [&](int t, Step& cur, Step& nxt) {
    const int sl = t & (PF - 1);
    const int sln = (t + 1) & (PF - 1);

    // slot sl was ds_read last iteration (as that iter's read-ahead): drain
    // before overwriting it with step t+PF's data.
    asm volatile("s_waitcnt lgkmcnt(0)" ::: "memory");
    if (t + PF < T_LEN) {
      const int goff = (t + PF) * DIM + hb + lane;
      gload_lds(Rp + goff, &lds[sl][0][0]);
      gload_lds(Wp + goff, &lds[sl][1][0]);
      gload_lds(Kp + goff, &lds[sl][2][0]);
      gload_lds(Vp + goff, &lds[sl][3][0]);
      gload_lds(Ap + goff, &lds[sl][4][0]);
      gload_lds(Bp + goff, &lds[sl][5][0]);
    }
    // Guarantee step t+1's 6 loads retired: that op has >=42 newer vmem ops
    // at every t (exactly 42 at t=0). Tail (no more issues): full drain.
    if (t < T_LEN - PF) {
      asm volatile("s_waitcnt vmcnt(42)" ::: "memory");
    } else {
      asm volatile("s_waitcnt vmcnt(0)" ::: "memory");
    }

    // read-ahead step t+1 operands (consumed next body; off critical path)
    nxt.r = *(float4*)&lds[sln][0][j0];
    nxt.w = *(float4*)&lds[sln][1][j0];
    nxt.k = *(float4*)&lds[sln][2][j0];
    nxt.v = lds[sln][3][row];
    nxt.a = *(float4*)&lds[sln][4][j0];
    nxt.b = *(float4*)&lds[sln][5][j0];

    // ---- step t ----
    float4 sw;  // S*w (feeds both P and the x-dot)
    sw.x = S.x * cur.w.x; sw.y = S.y * cur.w.y;
    sw.z = S.z * cur.w.z; sw.w = S.w * cur.w.w;

    float pa = dot4(S, cur.a);       // -> sa_i
    float pw = dot4(sw, cur.r);      // -> dot(S_old*w, r)
    float pb = dot4(cur.b, cur.r);   // -> b.r (row-redundant)
    float pk = dot4(cur.k, cur.r);   // -> k.r (row-redundant)

    float4 P;  // S*w + v*k, ready before sa arrives
    P.x = fmaf(cur.v, cur.k.x, sw.x); P.y = fmaf(cur.v, cur.k.y, sw.y);
    P.z = fmaf(cur.v, cur.k.z, sw.z); P.w = fmaf(cur.v, cur.k.w, sw.w);

    red16x4(pa, pw, pb, pk);

    float xo = fmaf(cur.v, pk, fmaf(pa, pb, pw));

    S.x = fmaf(pa, cur.b.x, P.x); S.y = fmaf(pa, cur.b.y, P.y);
    S.z = fmaf(pa, cur.b.z, P.z); S.w = fmaf(pa, cur.b.w, P.w);

    if (cg == 0) OUT[(long)t * DIM + hb + row] = xo;
  };

  for (int t = 0; t < T_LEN; t += 2) {
    body(t, c0, c1);
    body(t + 1, c1, c0);
  }

  // final state2 [H, N, N] after the x block
  *(float4*)(OUT + (size_t)X_SIZE + (size_t)head * HS * HS + row * HS + j0) = S;
}

extern "C" void kernel_launch(void* const* d_in, const int* in_sizes, int n_in,
                              void* d_out, int out_size, void* d_ws, size_t ws_size,
                              hipStream_t stream) {
  // inputs: 0=seq_length 1=r 2=w 3=k 4=v 5=a 6=b 7=state2
  const float* Rp = (const float*)d_in[1];
  const float* Wp = (const float*)d_in[2];
  const float* Kp = (const float*)d_in[3];
  const float* Vp = (const float*)d_in[4];
  const float* Ap = (const float*)d_in[5];
  const float* Bp = (const float*)d_in[6];
  const float* S0 = (const float*)d_in[7];
  wkv7_kernel<<<dim3(512), dim3(64), 0, stream>>>(Rp, Wp, Kp, Vp, Ap, Bp, S0,
                                                  (float*)d_out);
}

// Round 3
// 1039.814 us; speedup vs baseline: 2.7169x; 2.4968x over previous
//
#include <hip/hip_runtime.h>

// RWKV-7 WKV recurrence. T=4096, H=32 heads, N=64 head size, f32.
// Per head-row i: sa_i = dot(S[i], a); S[i] = S[i]*w + sa_i*b + v_i*k;
//                 x_i = dot(S[i], r)  [factored: dot(S*w,r) + sa*(b.r) + v*(k.r)]
// 512 blocks x 64 thr; wave = 4 rows x 16 colgroups (4 cols/lane) of one head.
// R2 change: NO LDS staging. Operands flow global->registers via an 8-deep
// fully-unrolled register ring; compiler-derived counted vmcnt (56 in-flight
// ops between def and use) keeps the pipe full. R1's global_load_lds staging
// retired ~1 op/200cyc -> 1300 cyc/step stall (VALUBusy 7.6%).

#define T_LEN 4096
#define NH 32
#define HS 64
#define DIM (NH * HS)   // 2048
#define RING 8          // 8 steps x (6 loads + 1 store) = 56 vmem in flight <= 63
#define X_SIZE (T_LEN * DIM)

template <int CTRL>
__device__ __forceinline__ float dppadd(float x) {
  int v = __builtin_amdgcn_update_dpp(0, __float_as_int(x), CTRL, 0xF, 0xF, true);
  return x + __int_as_float(v);
}

// Four parallel 16-lane butterfly sums, level-interleaved for ILP. Pure DPP.
__device__ __forceinline__ void red16x4(float& a, float& b, float& c, float& d) {
  a = dppadd<0xB1>(a);  b = dppadd<0xB1>(b);  c = dppadd<0xB1>(c);  d = dppadd<0xB1>(d);   // quad_perm xor1
  a = dppadd<0x4E>(a);  b = dppadd<0x4E>(b);  c = dppadd<0x4E>(c);  d = dppadd<0x4E>(d);   // quad_perm xor2
  a = dppadd<0x124>(a); b = dppadd<0x124>(b); c = dppadd<0x124>(c); d = dppadd<0x124>(d);  // row_ror:4
  a = dppadd<0x128>(a); b = dppadd<0x128>(b); c = dppadd<0x128>(c); d = dppadd<0x128>(d);  // row_ror:8
}

__device__ __forceinline__ float dot4(const float4& x, const float4& y) {
  return x.x * y.x + x.y * y.y + x.z * y.z + x.w * y.w;
}

struct Step {
  float4 r, w, k, a, b;  // per-lane column fragment j0..j0+3
  float v;               // per-row scalar
};

__global__ void __launch_bounds__(64, 1) wkv7_kernel(
    const float* __restrict__ Rp, const float* __restrict__ Wp,
    const float* __restrict__ Kp, const float* __restrict__ Vp,
    const float* __restrict__ Ap, const float* __restrict__ Bp,
    const float* __restrict__ S0, float* __restrict__ OUT) {
  // XCD-aware: each head's 16 blocks stay on one XCD for L2 line sharing.
  const int bid = blockIdx.x;              // 0..511
  const int xcd = bid & 7;
  const int slot = bid >> 3;               // 0..63
  const int head = xcd * 4 + (slot >> 4);  // 4 heads per XCD
  const int rowblk = slot & 15;
  const int lane = threadIdx.x & 63;
  const int cg = lane & 15;                // colgroup: cols cg*4..cg*4+3
  const int tr = lane >> 4;
  const int row = rowblk * 4 + tr;         // 0..63 within head
  const int j0 = cg * 4;
  const int hb = head * HS;
  const int off4 = hb + j0;                // col-fragment element offset
  const int offv = hb + row;               // v element offset

  // state row fragment S[row][j0..j0+3]
  float4 S = *(const float4*)(S0 + (size_t)head * HS * HS + row * HS + j0);

  Step ring[RING];  // fully-unrolled indexing only (constant indices)

  auto fill = [&](int t, Step& s) {
    const size_t base = (size_t)t * DIM;
    s.r = *(const float4*)(Rp + base + off4);
    s.w = *(const float4*)(Wp + base + off4);
    s.k = *(const float4*)(Kp + base + off4);
    s.a = *(const float4*)(Ap + base + off4);
    s.b = *(const float4*)(Bp + base + off4);
    s.v = Vp[base + offv];
  };

#pragma unroll
  for (int p = 0; p < RING; ++p) fill(p, ring[p]);

  for (int t0 = 0; t0 < T_LEN; t0 += RING) {
#pragma unroll
    for (int u = 0; u < RING; ++u) {
      const int t = t0 + u;

      // ---- step t (consume ring[u]) ----
      float4 sw;  // S*w feeds both the x-dot and the state update
      sw.x = S.x * ring[u].w.x; sw.y = S.y * ring[u].w.y;
      sw.z = S.z * ring[u].w.z; sw.w = S.w * ring[u].w.w;

      float pa = dot4(S, ring[u].a);            // -> sa_i
      float pw = dot4(sw, ring[u].r);           // -> dot(S*w, r)
      float pb = dot4(ring[u].b, ring[u].r);    // -> b.r (row-uniform)
      float pk = dot4(ring[u].k, ring[u].r);    // -> k.r (row-uniform)

      float4 P;  // S*w + v*k, ready before sa arrives
      P.x = fmaf(ring[u].v, ring[u].k.x, sw.x);
      P.y = fmaf(ring[u].v, ring[u].k.y, sw.y);
      P.z = fmaf(ring[u].v, ring[u].k.z, sw.z);
      P.w = fmaf(ring[u].v, ring[u].k.w, sw.w);

      const float cv = ring[u].v;
      const float4 cb = ring[u].b;

      // ---- refill ring[u] with step t+RING (issue loads; used 8 steps later,
      // compiler emits counted vmcnt across the ~56 intervening vmem ops) ----
      int tp = t + RING;
      tp = tp < T_LEN ? tp : T_LEN - 1;  // harmless refetch on the last round
      fill(tp, ring[u]);

      red16x4(pa, pw, pb, pk);

      float xo = fmaf(cv, pk, fmaf(pa, pb, pw));

      S.x = fmaf(pa, cb.x, P.x); S.y = fmaf(pa, cb.y, P.y);
      S.z = fmaf(pa, cb.z, P.z); S.w = fmaf(pa, cb.w, P.w);

      if (cg == 0) OUT[(size_t)t * DIM + hb + row] = xo;
    }
  }

  // final state2 [H, N, N] after the x block
  *(float4*)(OUT + (size_t)X_SIZE + (size_t)head * HS * HS + row * HS + j0) = S;
}

extern "C" void kernel_launch(void* const* d_in, const int* in_sizes, int n_in,
                              void* d_out, int out_size, void* d_ws, size_t ws_size,
                              hipStream_t stream) {
  // inputs: 0=seq_length 1=r 2=w 3=k 4=v 5=a 6=b 7=state2
  const float* Rp = (const float*)d_in[1];
  const float* Wp = (const float*)d_in[2];
  const float* Kp = (const float*)d_in[3];
  const float* Vp = (const float*)d_in[4];
  const float* Ap = (const float*)d_in[5];
  const float* Bp = (const float*)d_in[6];
  const float* S0 = (const float*)d_in[7];
  wkv7_kernel<<<dim3(512), dim3(64), 0, stream>>>(Rp, Wp, Kp, Vp, Ap, Bp, S0,
                                                  (float*)d_out);
}